// Round 6
// baseline (766.926 us; speedup 1.0000x reference)
//
#include <hip/hip_runtime.h>
#include <stddef.h>

#define TT 2048
#define NN 4096
#define LSEG 64
#define NSEG (TT / LSEG)   // 32
#define TPA1 1024          // phase A: ONE block, 1024 threads (16 waves, 1 CU)
#define TPA 64
#define NPT 4              // neurons per thread (TPA1 * NPT == NN)
#define TPB 256
#define WCAP 256           // fire-list capacity (>= max_spikes)
#define RING 8             // inp prefetch ring depth (rows in flight)
#define MAXU 0xFFFFFFFFu
#define NOFIRE 0xFFFFFFFEu

// ---------------- Phase A: exact coupled sim, events-only, SINGLE BLOCK ----------
// 1 block x 1024 threads (16 waves on one CU), 4 neurons/thread, state in regs.
// NO cross-block protocol, NO ys writes. Outputs: fire list + t_stop/nsp -> hdr.
// Per-step sync = wave shfl-min -> 16-slot LDS publish -> RAW s_barrier with
// lgkmcnt-only wait (NOT __syncthreads: no vmcnt(0) drain, so the inp ring's
// global loads and the w-row gathers stay in flight across barriers - this was
// round-1's killer). LDS slots double-buffered by step parity (one barrier/step).
// w-gather issued on the fire step, consumed next step's drift (1-step slack);
// ru loaded scattered, only for local-event lanes (rare), issued early.
__global__ __launch_bounds__(TPA1) void phaseA(
    const float* __restrict__ ts, const float* __restrict__ inp,
    const float* __restrict__ w, const float* __restrict__ v0,
    const float* __restrict__ i0, const float* __restrict__ mu,
    const float* __restrict__ s0u, const float* __restrict__ ru,
    const int* __restrict__ mx, unsigned int* __restrict__ hdr,
    unsigned int* __restrict__ fireT, unsigned int* __restrict__ fireIdx)
{
#pragma clang fp contract(off)
  const int tid = threadIdx.x;          // 0..1023
  const int wid = tid >> 6;             // wave id 0..15
  const int lane = tid & 63;
  const int n0 = tid * NPT;
  const float dt = ts[1] - ts[0];
  const float mu1 = mu[0], mu2 = mu[1];
  const int maxs = mx[0];

  const float4* inp4 = (const float4*)inp;
  const float4* w4   = (const float4*)w;

  float4 a4;
  a4 = ((const float4*)v0)[tid];  float v[NPT]    = {a4.x, a4.y, a4.z, a4.w};
  a4 = ((const float4*)i0)[tid];  float i_nw[NPT] = {a4.x, a4.y, a4.z, a4.w};
  a4 = ((const float4*)s0u)[tid];
  float s[NPT] = {logf(a4.x + 1e-12f) - 0.01f, logf(a4.y + 1e-12f) - 0.01f,
                  logf(a4.z + 1e-12f) - 0.01f, logf(a4.w + 1e-12f) - 0.01f};

  float wv[NPT] = {0.f, 0.f, 0.f, 0.f};     // w[gm(t-1)] slice (issued last step)
  bool  aw[NPT] = {false, false, false, false};
  int nsp = 0;
  int t_stop = TT;

  __shared__ unsigned int shw[2][16];       // per-wave minima, parity dbuf

  // preload inp ring: rows 0..RING-1 (16 B/thread/row, coalesced)
  float4 ib[RING];
#pragma unroll
  for (int j = 0; j < RING; ++j) ib[j] = inp4[(size_t)j * (NN / 4) + tid];

  for (int tb = 0; tb < TT; tb += RING) {
#pragma unroll
    for (int j = 0; j < RING; ++j) {
      const int t = tb + j;
      const float4 cur = ib[j];
      if (t + RING < TT)                    // refill slot (static index - reg ring)
        ib[j] = inp4[(size_t)(t + RING) * (NN / 4) + tid];

      // ---- ev-phase: s_n(t), ev(t) from v(t), s(t); scattered ru for ev lanes
      float sn[NPT], rv[NPT];
      bool ev[NPT];
      unsigned int m = NOFIRE;
#pragma unroll
      for (int k = 0; k < NPT; ++k) {
        float sig = 1.0f / (1.0f + expf(-v[k]));
        sn[k] = s[k] + dt * sig;
        ev[k] = sn[k] >= 0.0f;
        unsigned int c = ev[k] ? (unsigned int)(n0 + k) : NOFIRE;
        m = m < c ? m : c;
        rv[k] = ev[k] ? ru[(size_t)t * NN + (n0 + k)] : 0.0f;  // rare, early-issued
      }

      // ---- wave min -> LDS publish -> raw barrier (lgkm-only; vmem stays in flight)
#pragma unroll
      for (int off = 32; off > 0; off >>= 1) {
        unsigned int o = (unsigned int)__shfl_down((int)m, off, 64);
        m = m < o ? m : o;
      }
      const int p = t & 1;
      if (lane == 0) shw[p][wid] = m;
      asm volatile("s_waitcnt lgkmcnt(0)" ::: "memory");
      __builtin_amdgcn_sched_barrier(0);
      __builtin_amdgcn_s_barrier();
      __builtin_amdgcn_sched_barrier(0);

      unsigned int gm;
      {
        const uint4* sp = (const uint4*)&shw[p][0];
        uint4 q0 = sp[0], q1 = sp[1], q2 = sp[2], q3 = sp[3];
        unsigned int m0 = q0.x < q0.y ? q0.x : q0.y;
        unsigned int m1 = q0.z < q0.w ? q0.z : q0.w;
        unsigned int m2 = q1.x < q1.y ? q1.x : q1.y;
        unsigned int m3 = q1.z < q1.w ? q1.z : q1.w;
        unsigned int m4 = q2.x < q2.y ? q2.x : q2.y;
        unsigned int m5 = q2.z < q2.w ? q2.z : q2.w;
        unsigned int m6 = q3.x < q3.y ? q3.x : q3.y;
        unsigned int m7 = q3.z < q3.w ? q3.z : q3.w;
        m0 = m0 < m1 ? m0 : m1;  m2 = m2 < m3 ? m2 : m3;
        m4 = m4 < m5 ? m4 : m5;  m6 = m6 < m7 ? m6 : m7;
        m0 = m0 < m2 ? m0 : m2;  m4 = m4 < m6 ? m4 : m6;
        gm = m0 < m4 ? m0 : m4;
      }
      const bool fire = (gm < (unsigned int)NN) && (nsp < maxs);

      // ---- resolve i(t) (w-add from fire(t-1), gather issued last step);
      //      drift + transition of step t (reference op order)
      float iv[NPT] = {cur.x, cur.y, cur.z, cur.w};
#pragma unroll
      for (int k = 0; k < NPT; ++k) {
        float ifull = aw[k] ? (i_nw[k] + wv[k]) : i_nw[k];
        float vn  = v[k] + dt * (mu1 * (ifull - v[k]) + mu1 * iv[k]);
        float in_ = ifull + dt * (-mu2 * ifull);
        if (fire) {
          if (ev[k]) {
            v[k] = vn - 1.0f;
            s[k] = logf(rv[k] + 1e-12f) - 0.01f;   // logf only on rare ev path
            aw[k] = false;
          } else {
            v[k] = vn; s[k] = sn[k]; aw[k] = true; // w-add pending (next step)
          }
        } else {
          v[k] = vn; s[k] = sn[k]; aw[k] = false;
        }
        i_nw[k] = in_;
      }
      if (fire) {
        float4 wr = w4[(size_t)gm * (NN / 4) + tid];  // consumed next step (slack)
        wv[0] = wr.x; wv[1] = wr.y; wv[2] = wr.z; wv[3] = wr.w;
        if (tid == 0 && nsp < WCAP) {
          fireT[nsp] = (unsigned int)t;
          fireIdx[nsp] = gm;
        }
        ++nsp;
        if (nsp >= maxs) {   // closed-form t_stop: first L-multiple >= t+1
          t_stop = ((t + 1 + LSEG - 1) >> 6) << 6;
          if (t_stop > TT) t_stop = TT;
          goto done;
        }
      }
    }
  }
done:
  if (tid == 0) { hdr[0] = (unsigned int)t_stop; hdr[1] = (unsigned int)nsp; }
}

// ---------------- Phase A2: parallel replay of [0, K') with known schedule -------
// (unchanged from round 3 - verified passing)
__global__ __launch_bounds__(TPA) void phaseA2(
    const float* __restrict__ ts, const float* __restrict__ inp,
    const float* __restrict__ w, const float* __restrict__ v0,
    const float* __restrict__ i0, const float* __restrict__ mu,
    const float* __restrict__ s0u, const float* __restrict__ ru,
    const unsigned int* __restrict__ hdr, const unsigned int* __restrict__ fireT,
    const unsigned int* __restrict__ fireIdx, float* __restrict__ ys)
{
#pragma clang fp contract(off)
  const int tid = threadIdx.x;
  const int n = blockIdx.x * TPA + tid;
  const int Kp = (int)hdr[0];
  int nf = (int)hdr[1]; if (nf > WCAP) nf = WCAP;
  const float dt = ts[1] - ts[0];
  const float mu1 = mu[0], mu2 = mu[1];

  __shared__ unsigned int sT[WCAP];
  __shared__ float wlds[WCAP][TPA];
  for (int k = tid; k < nf; k += TPA) sT[k] = fireT[k];
  for (int k0 = 0; k0 < nf; k0 += 8) {
    float tmp[8];
#pragma unroll
    for (int j = 0; j < 8; ++j) {
      int k = k0 + j;
      tmp[j] = (k < nf) ? w[(size_t)fireIdx[k] * NN + n] : 0.0f;
    }
#pragma unroll
    for (int j = 0; j < 8; ++j) {
      int k = k0 + j;
      if (k < nf) wlds[k][tid] = tmp[j];
    }
  }
  __syncthreads();

  float v = v0[n];
  float i = i0[n];
  float s = logf(s0u[n] + 1e-12f) - 0.01f;

  float ib[8], rb[8];
#pragma unroll
  for (int j = 0; j < 8; ++j) {
    ib[j] = inp[(size_t)j * NN + n];
    rb[j] = ru[(size_t)j * NN + n];
  }
  int kp = 0;
  for (int tb = 0; tb < Kp; tb += 8) {
#pragma unroll
    for (int j = 0; j < 8; ++j) {
      const int t = tb + j;
      const float x   = ib[j];
      const float ruv = rb[j];
      if (t + 8 < Kp) {
        ib[j] = inp[(size_t)(t + 8) * NN + n];
        rb[j] = ru[(size_t)(t + 8) * NN + n];
      }
      float sig = 1.0f / (1.0f + expf(-v));
      float sn = s + dt * sig;
      bool e = sn >= 0.0f;
      float vn  = v + dt * (mu1 * (i - v) + mu1 * x);
      float in_ = i + dt * (-mu2 * i);
      bool fire = (kp < nf) && (sT[kp] == (unsigned int)t);
      if (fire) {
        float wc = wlds[kp][tid];
        ++kp;
        if (e) { v = vn - 1.0f; i = in_;      s = logf(ruv + 1e-12f) - 0.01f; }
        else   { v = vn;        i = in_ + wc; s = sn; }
      } else   { v = vn;        i = in_;      s = sn; }
      size_t o = ((size_t)t * NN + n) * 3;
      *(float3*)(ys + o) = make_float3(v, i, s);
    }
  }
}

// ---------------- Phase B: decoupled closed-form tail (unchanged) ----------------
__global__ __launch_bounds__(TPB) void p1_segc(
    const float* __restrict__ ts, const float* __restrict__ inp,
    const float* __restrict__ mu, const float* __restrict__ ys,
    const unsigned int* __restrict__ hdr, float* __restrict__ buf1)
{
  unsigned int Kp = hdr[0];
  unsigned int g0 = Kp / LSEG;
  unsigned int g = blockIdx.x >> 4;
  if (g < g0) return;
  int n = (blockIdx.x & 15) * TPB + threadIdx.x;
  float dt = ts[1] - ts[0];
  float mu1 = mu[0], mu2 = mu[1];
  float a = 1.0f - dt * mu1, b = dt * mu1, r = 1.0f - dt * mu2;
  float ibase = ys[((size_t)(Kp - 1) * NN + n) * 3 + 1];
  float ij = ibase * powf(r, (float)((int)(g * LSEG) - (int)Kp));
  float c = 0.0f;
  size_t base = (size_t)(g * LSEG) * NN + n;
  for (int j = 0; j < LSEG; ++j) {
    float x = inp[base + (size_t)j * NN];
    c = a * c + b * (ij + x);
    ij *= r;
  }
  buf1[(size_t)g * NN + n] = c;
}

__global__ __launch_bounds__(TPB) void p2_scanv(
    const float* __restrict__ ts, const float* __restrict__ mu,
    const float* __restrict__ ys, const unsigned int* __restrict__ hdr,
    float* __restrict__ buf1)
{
  unsigned int Kp = hdr[0];
  unsigned int g0 = Kp / LSEG;
  if (g0 >= NSEG) return;
  int n = blockIdx.x * TPB + threadIdx.x;
  float dt = ts[1] - ts[0];
  float mu1 = mu[0];
  float a = 1.0f - dt * mu1;
  float aL = a;
  for (int k = 0; k < 6; ++k) aL *= aL;   // a^64
  float v = ys[((size_t)(Kp - 1) * NN + n) * 3 + 0];
  for (unsigned int g = g0; g < NSEG; ++g) {
    float cg = buf1[(size_t)g * NN + n];
    buf1[(size_t)g * NN + n] = v;
    v = aL * v + cg;
  }
}

__global__ __launch_bounds__(TPB) void p3_seg(
    const float* __restrict__ ts, const float* __restrict__ inp,
    const float* __restrict__ mu, const unsigned int* __restrict__ hdr,
    const float* __restrict__ buf1, float* __restrict__ buf2,
    float* __restrict__ ys)
{
  unsigned int Kp = hdr[0];
  unsigned int g0 = Kp / LSEG;
  unsigned int g = blockIdx.x >> 4;
  if (g < g0) return;
  int n = (blockIdx.x & 15) * TPB + threadIdx.x;
  float dt = ts[1] - ts[0];
  float mu1 = mu[0], mu2 = mu[1];
  float r = 1.0f - dt * mu2;
  float v = buf1[(size_t)g * NN + n];
  float ibase = ys[((size_t)(Kp - 1) * NN + n) * 3 + 1];
  float i = ibase * powf(r, (float)((int)(g * LSEG) - (int)Kp));
  float sl = 0.0f;
  for (int j = 0; j < LSEG; ++j) {
    size_t t = (size_t)g * LSEG + j;
    float x = inp[t * NN + n];
    float sig = 1.0f / (1.0f + expf(-v));
    sl = sl + dt * sig;
    float vn  = v + dt * (mu1 * (i - v) + mu1 * x);
    float in_ = i + dt * (-mu2 * i);
    size_t o = (t * NN + n) * 3;
    ys[o] = vn; ys[o + 1] = in_; ys[o + 2] = sl;
    v = vn; i = in_;
  }
  buf2[(size_t)g * NN + n] = sl;
}

__global__ __launch_bounds__(TPB) void p4_scans(
    const float* __restrict__ ys, const unsigned int* __restrict__ hdr,
    float* __restrict__ buf2)
{
  unsigned int Kp = hdr[0];
  unsigned int g0 = Kp / LSEG;
  if (g0 >= NSEG) return;
  int n = blockIdx.x * TPB + threadIdx.x;
  float s = ys[((size_t)(Kp - 1) * NN + n) * 3 + 2];
  for (unsigned int g = g0; g < NSEG; ++g) {
    float t = buf2[(size_t)g * NN + n];
    buf2[(size_t)g * NN + n] = s;
    s += t;
  }
}

__global__ __launch_bounds__(TPB) void p5_fixs(
    const unsigned int* __restrict__ hdr, const float* __restrict__ buf2,
    float* __restrict__ ys)
{
  unsigned int Kp = hdr[0];
  size_t e = (size_t)Kp * NN + (size_t)blockIdx.x * TPB + threadIdx.x;
  if (e >= (size_t)TT * NN) return;
  unsigned int t = (unsigned int)(e >> 12);        // /NN
  unsigned int n = (unsigned int)(e & (NN - 1));
  unsigned int g = t >> 6;                         // /LSEG
  ys[e * 3 + 2] += buf2[(size_t)g * NN + n];
}

extern "C" void kernel_launch(void* const* d_in, const int* in_sizes, int n_in,
                              void* d_out, int out_size, void* d_ws, size_t ws_size,
                              hipStream_t stream)
{
  (void)in_sizes; (void)n_in; (void)out_size; (void)ws_size;
  const float* ts  = (const float*)d_in[0];
  const float* inp = (const float*)d_in[1];
  const float* w   = (const float*)d_in[2];
  const float* v0  = (const float*)d_in[3];
  const float* i0  = (const float*)d_in[4];
  const float* mu  = (const float*)d_in[5];
  const float* s0u = (const float*)d_in[6];
  const float* ru  = (const float*)d_in[7];
  const int*   mx  = (const int*)d_in[8];
  float* ys = (float*)d_out;

  char* wsb = (char*)d_ws;
  unsigned int* hdr     = (unsigned int*)wsb;               // 8 B used
  unsigned int* fireT   = (unsigned int*)(wsb + 256);       // 1 KB (WCAP)
  unsigned int* fireIdx = (unsigned int*)(wsb + 1280);      // 1 KB
  float* buf1 = (float*)(wsb + 4096);                       // NSEG*NN*4 = 512 KB
  float* buf2 = buf1 + (size_t)NSEG * NN;                   // 512 KB

  // single-block events-only phase A: no slots, no memsets, no protocol
  phaseA<<<1, TPA1, 0, stream>>>(ts, inp, w, v0, i0, mu, s0u, ru, mx,
                                 hdr, fireT, fireIdx);
  phaseA2<<<NN / TPA, TPA, 0, stream>>>(ts, inp, w, v0, i0, mu, s0u, ru,
                                        hdr, fireT, fireIdx, ys);
  p1_segc<<<NSEG * 16, TPB, 0, stream>>>(ts, inp, mu, ys, hdr, buf1);
  p2_scanv<<<NN / TPB, TPB, 0, stream>>>(ts, mu, ys, hdr, buf1);
  p3_seg<<<NSEG * 16, TPB, 0, stream>>>(ts, inp, mu, hdr, buf1, buf2, ys);
  p4_scans<<<NN / TPB, TPB, 0, stream>>>(ys, hdr, buf2);
  p5_fixs<<<(TT - 128) * NN / TPB, TPB, 0, stream>>>(hdr, buf2, ys);
}

// Round 10
// 633.617 us; speedup vs baseline: 1.2104x; 1.2104x over previous
//
#include <hip/hip_runtime.h>
#include <stddef.h>

#define TT 2048
#define NN 4096
#define LSEG 64
#define NSEG (TT / LSEG)   // 32
#define TPA1 1024          // phase A: ONE block, 1024 threads (16 waves, 1 CU)
#define TPA 64
#define NPT 4              // neurons per thread (TPA1 * NPT == NN)
#define TPB 256
#define WCAP 256           // fire-list capacity (>= max_spikes)
#define RING 8             // inp/ru prefetch ring depth (rows in flight)
#define MAXU 0xFFFFFFFFu
#define NOFIRE 0xFFFFFFFEu

// ---------------- Phase A: exact coupled sim, events-only, SINGLE BLOCK ----------
// 1 block x 1024 threads (16 waves on one CU), 4 neurons/thread, state in regs.
// Outputs ONLY the fire schedule + t_stop/nsp. Raw s_barrier with lgkm-only wait.
// ROUND-7 FIX: ru is now an 8-deep coalesced float4 ring like inp (round 6's
// scattered same-step ru loads forced an effective vmcnt(0) drain of the whole
// vmem queue every step - the 2.16us/step stall). All vmem consumed in the loop
// is now >=1 step old (w gather) or 8 steps old (rings): no fresh-load waits.
// Ring refills are issued in the barrier shadow.
__global__ __launch_bounds__(TPA1) void phaseA(
    const float* __restrict__ ts, const float* __restrict__ inp,
    const float* __restrict__ w, const float* __restrict__ v0,
    const float* __restrict__ i0, const float* __restrict__ mu,
    const float* __restrict__ s0u, const float* __restrict__ ru,
    const int* __restrict__ mx, unsigned int* __restrict__ hdr,
    unsigned int* __restrict__ fireT, unsigned int* __restrict__ fireIdx)
{
#pragma clang fp contract(off)
  const int tid = threadIdx.x;          // 0..1023
  const int wid = tid >> 6;             // wave id 0..15
  const int lane = tid & 63;
  const int n0 = tid * NPT;
  const float dt = ts[1] - ts[0];
  const float mu1 = mu[0], mu2 = mu[1];
  const int maxs = mx[0];

  const float4* inp4 = (const float4*)inp;
  const float4* ru4  = (const float4*)ru;
  const float4* w4   = (const float4*)w;

  float4 a4;
  a4 = ((const float4*)v0)[tid];  float v[NPT]    = {a4.x, a4.y, a4.z, a4.w};
  a4 = ((const float4*)i0)[tid];  float i_nw[NPT] = {a4.x, a4.y, a4.z, a4.w};
  a4 = ((const float4*)s0u)[tid];
  float s[NPT] = {logf(a4.x + 1e-12f) - 0.01f, logf(a4.y + 1e-12f) - 0.01f,
                  logf(a4.z + 1e-12f) - 0.01f, logf(a4.w + 1e-12f) - 0.01f};

  float wv[NPT] = {0.f, 0.f, 0.f, 0.f};     // w[gm(t-1)] slice (issued last step)
  bool  aw[NPT] = {false, false, false, false};
  int nsp = 0;
  int t_stop = TT;

  __shared__ unsigned int shw[2][16];       // per-wave minima, parity dbuf

  // preload rings: rows 0..RING-1 (16 B/thread/row, coalesced)
  float4 ib[RING], rb[RING];
#pragma unroll
  for (int j = 0; j < RING; ++j) {
    ib[j] = inp4[(size_t)j * (NN / 4) + tid];
    rb[j] = ru4[(size_t)j * (NN / 4) + tid];
  }

  for (int tb = 0; tb < TT; tb += RING) {
#pragma unroll
    for (int j = 0; j < RING; ++j) {
      const int t = tb + j;
      const float4 cur  = ib[j];            // inp row t (8 steps old: free wait)
      const float4 rrow = rb[j];            // ru  row t (8 steps old: free wait)

      // ---- ev-phase: pure VALU (expf + precise div + fma + cmp), no vmem
      float sn[NPT];
      bool ev[NPT];
      unsigned int m = NOFIRE;
#pragma unroll
      for (int k = 0; k < NPT; ++k) {
        float sig = 1.0f / (1.0f + expf(-v[k]));
        sn[k] = s[k] + dt * sig;
        ev[k] = sn[k] >= 0.0f;
        unsigned int c = ev[k] ? (unsigned int)(n0 + k) : NOFIRE;
        m = m < c ? m : c;
      }

      // ---- wave min -> LDS publish -> raw barrier (lgkm-only; vmem in flight)
#pragma unroll
      for (int off = 32; off > 0; off >>= 1) {
        unsigned int o = (unsigned int)__shfl_down((int)m, off, 64);
        m = m < o ? m : o;
      }
      const int p = t & 1;
      if (lane == 0) shw[p][wid] = m;
      asm volatile("s_waitcnt lgkmcnt(0)" ::: "memory");
      __builtin_amdgcn_sched_barrier(0);
      __builtin_amdgcn_s_barrier();
      __builtin_amdgcn_sched_barrier(0);

      // ---- ring refills in the barrier shadow (consumed at t+RING)
      if (t + RING < TT) {
        ib[j] = inp4[(size_t)(t + RING) * (NN / 4) + tid];
        rb[j] = ru4[(size_t)(t + RING) * (NN / 4) + tid];
      }

      unsigned int gm;
      {
        const uint4* sp = (const uint4*)&shw[p][0];
        uint4 q0 = sp[0], q1 = sp[1], q2 = sp[2], q3 = sp[3];
        unsigned int m0 = q0.x < q0.y ? q0.x : q0.y;
        unsigned int m1 = q0.z < q0.w ? q0.z : q0.w;
        unsigned int m2 = q1.x < q1.y ? q1.x : q1.y;
        unsigned int m3 = q1.z < q1.w ? q1.z : q1.w;
        unsigned int m4 = q2.x < q2.y ? q2.x : q2.y;
        unsigned int m5 = q2.z < q2.w ? q2.z : q2.w;
        unsigned int m6 = q3.x < q3.y ? q3.x : q3.y;
        unsigned int m7 = q3.z < q3.w ? q3.z : q3.w;
        m0 = m0 < m1 ? m0 : m1;  m2 = m2 < m3 ? m2 : m3;
        m4 = m4 < m5 ? m4 : m5;  m6 = m6 < m7 ? m6 : m7;
        m0 = m0 < m2 ? m0 : m2;  m4 = m4 < m6 ? m4 : m6;
        gm = m0 < m4 ? m0 : m4;
      }
      const bool fire = (gm < (unsigned int)NN) && (nsp < maxs);

      // ---- resolve i(t) (w-add from fire(t-1), gather issued last step);
      //      drift + transition of step t (reference op order)
      float iv[NPT] = {cur.x, cur.y, cur.z, cur.w};
      float rv[NPT] = {rrow.x, rrow.y, rrow.z, rrow.w};
#pragma unroll
      for (int k = 0; k < NPT; ++k) {
        float ifull = aw[k] ? (i_nw[k] + wv[k]) : i_nw[k];
        float vn  = v[k] + dt * (mu1 * (ifull - v[k]) + mu1 * iv[k]);
        float in_ = ifull + dt * (-mu2 * ifull);
        if (fire) {
          if (ev[k]) {
            v[k] = vn - 1.0f;
            s[k] = logf(rv[k] + 1e-12f) - 0.01f;   // logf only on rare ev path
            aw[k] = false;
          } else {
            v[k] = vn; s[k] = sn[k]; aw[k] = true; // w-add pending (next step)
          }
        } else {
          v[k] = vn; s[k] = sn[k]; aw[k] = false;
        }
        i_nw[k] = in_;
      }
      if (fire) {
        float4 wr = w4[(size_t)gm * (NN / 4) + tid];  // consumed next step (slack)
        wv[0] = wr.x; wv[1] = wr.y; wv[2] = wr.z; wv[3] = wr.w;
        if (tid == 0 && nsp < WCAP) {
          fireT[nsp] = (unsigned int)t;
          fireIdx[nsp] = gm;
        }
        ++nsp;
        if (nsp >= maxs) {   // closed-form t_stop: first L-multiple >= t+1
          t_stop = ((t + 1 + LSEG - 1) >> 6) << 6;
          if (t_stop > TT) t_stop = TT;
          goto done;
        }
      }
    }
  }
done:
  if (tid == 0) { hdr[0] = (unsigned int)t_stop; hdr[1] = (unsigned int)nsp; }
}

// ---------------- Phase A2: parallel replay of [0, K') with known schedule -------
// (unchanged - verified passing)
__global__ __launch_bounds__(TPA) void phaseA2(
    const float* __restrict__ ts, const float* __restrict__ inp,
    const float* __restrict__ w, const float* __restrict__ v0,
    const float* __restrict__ i0, const float* __restrict__ mu,
    const float* __restrict__ s0u, const float* __restrict__ ru,
    const unsigned int* __restrict__ hdr, const unsigned int* __restrict__ fireT,
    const unsigned int* __restrict__ fireIdx, float* __restrict__ ys)
{
#pragma clang fp contract(off)
  const int tid = threadIdx.x;
  const int n = blockIdx.x * TPA + tid;
  const int Kp = (int)hdr[0];
  int nf = (int)hdr[1]; if (nf > WCAP) nf = WCAP;
  const float dt = ts[1] - ts[0];
  const float mu1 = mu[0], mu2 = mu[1];

  __shared__ unsigned int sT[WCAP];
  __shared__ float wlds[WCAP][TPA];
  for (int k = tid; k < nf; k += TPA) sT[k] = fireT[k];
  for (int k0 = 0; k0 < nf; k0 += 8) {
    float tmp[8];
#pragma unroll
    for (int j = 0; j < 8; ++j) {
      int k = k0 + j;
      tmp[j] = (k < nf) ? w[(size_t)fireIdx[k] * NN + n] : 0.0f;
    }
#pragma unroll
    for (int j = 0; j < 8; ++j) {
      int k = k0 + j;
      if (k < nf) wlds[k][tid] = tmp[j];
    }
  }
  __syncthreads();

  float v = v0[n];
  float i = i0[n];
  float s = logf(s0u[n] + 1e-12f) - 0.01f;

  float ib[8], rb[8];
#pragma unroll
  for (int j = 0; j < 8; ++j) {
    ib[j] = inp[(size_t)j * NN + n];
    rb[j] = ru[(size_t)j * NN + n];
  }
  int kp = 0;
  for (int tb = 0; tb < Kp; tb += 8) {
#pragma unroll
    for (int j = 0; j < 8; ++j) {
      const int t = tb + j;
      const float x   = ib[j];
      const float ruv = rb[j];
      if (t + 8 < Kp) {
        ib[j] = inp[(size_t)(t + 8) * NN + n];
        rb[j] = ru[(size_t)(t + 8) * NN + n];
      }
      float sig = 1.0f / (1.0f + expf(-v));
      float sn = s + dt * sig;
      bool e = sn >= 0.0f;
      float vn  = v + dt * (mu1 * (i - v) + mu1 * x);
      float in_ = i + dt * (-mu2 * i);
      bool fire = (kp < nf) && (sT[kp] == (unsigned int)t);
      if (fire) {
        float wc = wlds[kp][tid];
        ++kp;
        if (e) { v = vn - 1.0f; i = in_;      s = logf(ruv + 1e-12f) - 0.01f; }
        else   { v = vn;        i = in_ + wc; s = sn; }
      } else   { v = vn;        i = in_;      s = sn; }
      size_t o = ((size_t)t * NN + n) * 3;
      *(float3*)(ys + o) = make_float3(v, i, s);
    }
  }
}

// ---------------- Phase B: decoupled closed-form tail ----------------
// P1: per (neuron, segment): C = sum_j a^(L-1-j) * b * (i_j + inp_j), i_j geometric.
__global__ __launch_bounds__(TPB) void p1_segc(
    const float* __restrict__ ts, const float* __restrict__ inp,
    const float* __restrict__ mu, const float* __restrict__ ys,
    const unsigned int* __restrict__ hdr, float* __restrict__ buf1)
{
  unsigned int Kp = hdr[0];
  unsigned int g0 = Kp / LSEG;
  unsigned int g = blockIdx.x >> 4;
  if (g < g0) return;
  int n = (blockIdx.x & 15) * TPB + threadIdx.x;
  float dt = ts[1] - ts[0];
  float mu1 = mu[0], mu2 = mu[1];
  float a = 1.0f - dt * mu1, b = dt * mu1, r = 1.0f - dt * mu2;
  float ibase = ys[((size_t)(Kp - 1) * NN + n) * 3 + 1];
  float ij = ibase * powf(r, (float)((int)(g * LSEG) - (int)Kp));
  float c = 0.0f;
  size_t base = (size_t)(g * LSEG) * NN + n;
  for (int j = 0; j < LSEG; ++j) {
    float x = inp[base + (size_t)j * NN];
    c = a * c + b * (ij + x);
    ij *= r;
  }
  buf1[(size_t)g * NN + n] = c;
}

// P2: per neuron, scan segment-boundary v:  v_{g+1} = a^L v_g + C_g (in place -> Vb)
__global__ __launch_bounds__(TPB) void p2_scanv(
    const float* __restrict__ ts, const float* __restrict__ mu,
    const float* __restrict__ ys, const unsigned int* __restrict__ hdr,
    float* __restrict__ buf1)
{
  unsigned int Kp = hdr[0];
  unsigned int g0 = Kp / LSEG;
  if (g0 >= NSEG) return;
  int n = blockIdx.x * TPB + threadIdx.x;
  float dt = ts[1] - ts[0];
  float mu1 = mu[0];
  float a = 1.0f - dt * mu1;
  float aL = a;
  for (int k = 0; k < 6; ++k) aL *= aL;   // a^64
  float v = ys[((size_t)(Kp - 1) * NN + n) * 3 + 0];
  for (unsigned int g = g0; g < NSEG; ++g) {
    float cg = buf1[(size_t)g * NN + n];
    buf1[(size_t)g * NN + n] = v;
    v = aL * v + cg;
  }
}

// P3a: sigma-sum-only replay per (neuron, segment): identical trajectory
// arithmetic as p3b, but writes ONLY the segment sigma-sum to buf2. This lets
// p4's scan run BEFORE the full replay so p3b can write s directly with the
// segment offset - eliminating p5's ~180 MB strided RMW over ys.
__global__ __launch_bounds__(TPB) void p3a_sig(
    const float* __restrict__ ts, const float* __restrict__ inp,
    const float* __restrict__ mu, const unsigned int* __restrict__ hdr,
    const float* __restrict__ buf1, const float* __restrict__ ys,
    float* __restrict__ buf2)
{
  unsigned int Kp = hdr[0];
  unsigned int g0 = Kp / LSEG;
  unsigned int g = blockIdx.x >> 4;
  if (g < g0) return;
  int n = (blockIdx.x & 15) * TPB + threadIdx.x;
  float dt = ts[1] - ts[0];
  float mu1 = mu[0], mu2 = mu[1];
  float r = 1.0f - dt * mu2;
  float v = buf1[(size_t)g * NN + n];
  float ibase = ys[((size_t)(Kp - 1) * NN + n) * 3 + 1];
  float i = ibase * powf(r, (float)((int)(g * LSEG) - (int)Kp));
  float sl = 0.0f;
  for (int j = 0; j < LSEG; ++j) {
    size_t t = (size_t)g * LSEG + j;
    float x = inp[t * NN + n];
    float sig = 1.0f / (1.0f + expf(-v));
    sl = sl + dt * sig;
    float vn  = v + dt * (mu1 * (i - v) + mu1 * x);
    float in_ = i + dt * (-mu2 * i);
    v = vn; i = in_;
  }
  buf2[(size_t)g * NN + n] = sl;
}

// P4: per neuron, scan sigma-sums -> s at segment starts (in place -> Sb)
// (unchanged; buf2 now comes from p3a instead of p3)
__global__ __launch_bounds__(TPB) void p4_scans(
    const float* __restrict__ ys, const unsigned int* __restrict__ hdr,
    float* __restrict__ buf2)
{
  unsigned int Kp = hdr[0];
  unsigned int g0 = Kp / LSEG;
  if (g0 >= NSEG) return;
  int n = blockIdx.x * TPB + threadIdx.x;
  float s = ys[((size_t)(Kp - 1) * NN + n) * 3 + 2];
  for (unsigned int g = g0; g < NSEG; ++g) {
    float t = buf2[(size_t)g * NN + n];
    buf2[(size_t)g * NN + n] = s;
    s += t;
  }
}

// P3b: full replay writing v,i and s = sl + Sb[g] directly (p5's add folded in;
// `sl + sb` is the identical float add p5 performed on identical operands).
__global__ __launch_bounds__(TPB) void p3b_seg(
    const float* __restrict__ ts, const float* __restrict__ inp,
    const float* __restrict__ mu, const unsigned int* __restrict__ hdr,
    const float* __restrict__ buf1, const float* __restrict__ buf2,
    float* __restrict__ ys)
{
  unsigned int Kp = hdr[0];
  unsigned int g0 = Kp / LSEG;
  unsigned int g = blockIdx.x >> 4;
  if (g < g0) return;
  int n = (blockIdx.x & 15) * TPB + threadIdx.x;
  float dt = ts[1] - ts[0];
  float mu1 = mu[0], mu2 = mu[1];
  float r = 1.0f - dt * mu2;
  float v = buf1[(size_t)g * NN + n];
  float sb = buf2[(size_t)g * NN + n];
  float ibase = ys[((size_t)(Kp - 1) * NN + n) * 3 + 1];
  float i = ibase * powf(r, (float)((int)(g * LSEG) - (int)Kp));
  float sl = 0.0f;
  for (int j = 0; j < LSEG; ++j) {
    size_t t = (size_t)g * LSEG + j;
    float x = inp[t * NN + n];
    float sig = 1.0f / (1.0f + expf(-v));
    sl = sl + dt * sig;
    float vn  = v + dt * (mu1 * (i - v) + mu1 * x);
    float in_ = i + dt * (-mu2 * i);
    size_t o = (t * NN + n) * 3;
    ys[o] = vn; ys[o + 1] = in_; ys[o + 2] = sl + sb;
    v = vn; i = in_;
  }
}

extern "C" void kernel_launch(void* const* d_in, const int* in_sizes, int n_in,
                              void* d_out, int out_size, void* d_ws, size_t ws_size,
                              hipStream_t stream)
{
  (void)in_sizes; (void)n_in; (void)out_size; (void)ws_size;
  const float* ts  = (const float*)d_in[0];
  const float* inp = (const float*)d_in[1];
  const float* w   = (const float*)d_in[2];
  const float* v0  = (const float*)d_in[3];
  const float* i0  = (const float*)d_in[4];
  const float* mu  = (const float*)d_in[5];
  const float* s0u = (const float*)d_in[6];
  const float* ru  = (const float*)d_in[7];
  const int*   mx  = (const int*)d_in[8];
  float* ys = (float*)d_out;

  char* wsb = (char*)d_ws;
  unsigned int* hdr     = (unsigned int*)wsb;               // 8 B used
  unsigned int* fireT   = (unsigned int*)(wsb + 256);       // 1 KB (WCAP)
  unsigned int* fireIdx = (unsigned int*)(wsb + 1280);      // 1 KB
  float* buf1 = (float*)(wsb + 4096);                       // NSEG*NN*4 = 512 KB
  float* buf2 = buf1 + (size_t)NSEG * NN;                   // 512 KB

  // single-block events-only phase A: no slots, no memsets, no protocol
  phaseA<<<1, TPA1, 0, stream>>>(ts, inp, w, v0, i0, mu, s0u, ru, mx,
                                 hdr, fireT, fireIdx);
  phaseA2<<<NN / TPA, TPA, 0, stream>>>(ts, inp, w, v0, i0, mu, s0u, ru,
                                        hdr, fireT, fireIdx, ys);
  p1_segc<<<NSEG * 16, TPB, 0, stream>>>(ts, inp, mu, ys, hdr, buf1);
  p2_scanv<<<NN / TPB, TPB, 0, stream>>>(ts, mu, ys, hdr, buf1);
  p3a_sig<<<NSEG * 16, TPB, 0, stream>>>(ts, inp, mu, hdr, buf1, ys, buf2);
  p4_scans<<<NN / TPB, TPB, 0, stream>>>(ys, hdr, buf2);
  p3b_seg<<<NSEG * 16, TPB, 0, stream>>>(ts, inp, mu, hdr, buf1, buf2, ys);
}